// Round 1
// 1010.207 us; speedup vs baseline: 1.0050x; 1.0050x over previous
//
#include <hip/hip_runtime.h>

// Problem constants: B=2, S=2048, D=1024, H=16, HD=64
#define S_LEN 2048
#define NH 16
#define HDIM 64
#define DMODEL 1024
#define NTOK 4096  // B*S

typedef __attribute__((ext_vector_type(8))) short bf16x8;   // 8 bf16 = 4 VGPRs (MFMA A/B frag)
typedef __attribute__((ext_vector_type(4))) float f32x4;    // MFMA C/D frag

__device__ __forceinline__ unsigned short f2bf(float f) {
  union { float f; unsigned int u; } a; a.f = f;
  unsigned int u = a.u;
  u += 0x7FFFu + ((u >> 16) & 1u);   // RNE
  return (unsigned short)(u >> 16);
}

__device__ __forceinline__ void gld_lds16(const unsigned short* g, unsigned short* l) {
  auto gp = (const __attribute__((address_space(1))) unsigned short*)(g);
  auto lp = (__attribute__((address_space(3))) unsigned short*)(l);
  __builtin_amdgcn_global_load_lds(gp, lp, 16, 0, 0);   // 16B per lane, async to LDS
}

// ---------------------------------------------------------------------------
// fp32 -> bf16 convert (n multiple of 4)
// ---------------------------------------------------------------------------
__global__ __launch_bounds__(256) void cvt_kernel(const float* __restrict__ s,
                                                  unsigned short* __restrict__ d, int n) {
  int i = (blockIdx.x * 256 + threadIdx.x) * 4;
  if (i >= n) return;
  float4 v = *(const float4*)(s + i);
  ushort4 o;
  o.x = f2bf(v.x); o.y = f2bf(v.y); o.z = f2bf(v.z); o.w = f2bf(v.w);
  *(ushort4*)(d + i) = o;
}

// ---------------------------------------------------------------------------
// GEMM core: C(128x128) = A[M,K=1024] * B[N,K=1024]^T, bf16 inputs, K-loop BK=32.
// m97 structure: global_load_lds width16 staging, 8 ds_read_b128 + 16 MFMA / iter.
// ---------------------------------------------------------------------------
__device__ __forceinline__ void gemm_core_128(
    const unsigned short* __restrict__ A, const unsigned short* __restrict__ B,
    unsigned short* Al, unsigned short* Bl, int m0, int n0, int tid, f32x4 acc[4][4])
{
  const int lane = tid & 63;
  const int wm = ((tid >> 6) >> 1) * 64;
  const int wn = ((tid >> 6) & 1) * 64;
  const int l15 = lane & 15, quad = lane >> 4;
  const int row0 = tid >> 2, c8 = (tid & 3) * 8;
  for (int kk = 0; kk < DMODEL; kk += 32) {
    gld_lds16(A + (size_t)(m0 + row0) * DMODEL + kk + c8,      Al + tid * 8);
    gld_lds16(A + (size_t)(m0 + 64 + row0) * DMODEL + kk + c8, Al + (256 + tid) * 8);
    gld_lds16(B + (size_t)(n0 + row0) * DMODEL + kk + c8,      Bl + tid * 8);
    gld_lds16(B + (size_t)(n0 + 64 + row0) * DMODEL + kk + c8, Bl + (256 + tid) * 8);
    __syncthreads();   // compiler emits vmcnt(0) drain before s_barrier
    bf16x8 af[4], bfr[4];
#pragma unroll
    for (int i = 0; i < 4; i++) {
      af[i]  = *(const bf16x8*)(Al + (wm + i * 16 + l15) * 32 + quad * 8);
      bfr[i] = *(const bf16x8*)(Bl + (wn + i * 16 + l15) * 32 + quad * 8);
    }
#pragma unroll
    for (int i = 0; i < 4; i++)
#pragma unroll
      for (int j = 0; j < 4; j++)
        acc[i][j] = __builtin_amdgcn_mfma_f32_16x16x32_bf16(af[i], bfr[j], acc[i][j], 0, 0, 0);
    __syncthreads();
  }
}

// ---------------------------------------------------------------------------
// QKV projection: z=0 -> q (pre-scaled by 1/8), z=1 -> k, z=2 -> v transposed.
// q,k layout [B,H,S,HD]; vT layout [B,H,HD,S].
// C/D frag mapping (m89-verified): col = lane&15, row = quad*4 + reg.
// ---------------------------------------------------------------------------
__global__ __launch_bounds__(256) void gemm_qkv(
    const unsigned short* __restrict__ xb,
    const unsigned short* __restrict__ wq, const unsigned short* __restrict__ wk,
    const unsigned short* __restrict__ wv,
    const float* __restrict__ bq, const float* __restrict__ bk, const float* __restrict__ bv,
    unsigned short* __restrict__ q_ws, unsigned short* __restrict__ k_ws,
    unsigned short* __restrict__ vT_ws)
{
  __shared__ unsigned short Al[128 * 32];
  __shared__ unsigned short Bl[128 * 32];
  const int which = blockIdx.z;
  const unsigned short* W = which == 0 ? wq : (which == 1 ? wk : wv);
  const float* bias = which == 0 ? bq : (which == 1 ? bk : bv);
  const int m0 = blockIdx.y * 128, n0 = blockIdx.x * 128;
  const int tid = threadIdx.x, lane = tid & 63;
  const int wm = ((tid >> 6) >> 1) * 64, wn = ((tid >> 6) & 1) * 64;
  const int l15 = lane & 15, quad = lane >> 4;
  f32x4 acc[4][4] = {};
  gemm_core_128(xb, W, Al, Bl, m0, n0, tid, acc);
  const float scale = (which == 0) ? 0.125f : 1.0f;   // fold 1/sqrt(HD) into q
  unsigned short* qk_dst = (which == 0) ? q_ws : k_ws;
#pragma unroll
  for (int j = 0; j < 4; j++) {
    const int n = n0 + wn + j * 16 + l15;
    const float bb = bias[n];
    const int h = n >> 6, d = n & 63;
#pragma unroll
    for (int i = 0; i < 4; i++)
#pragma unroll
      for (int r = 0; r < 4; r++) {
        const int m = m0 + wm + i * 16 + quad * 4 + r;
        const int b = m >> 11, s = m & 2047;
        const unsigned short o = f2bf((acc[i][j][r] + bb) * scale);
        if (which == 2)
          vT_ws[((size_t)(b * NH + h) * HDIM + d) * S_LEN + s] = o;
        else
          qk_dst[((size_t)(b * NH + h) * S_LEN + s) * HDIM + d] = o;
      }
  }
}

// ---------------------------------------------------------------------------
// Fused attention, split-K version.
// Grid: 2048 blocks = 32 bh * 64 q-tiles of 32 rows. 256 threads = 4 waves:
//   wave w: row-group rowg = w>>1 (16 q rows), key-half khalf = w&1 (1024 cols).
// 8 blocks/CU * 4 waves = 32 waves/CU (grid was the occupancy cap at 1024 blocks).
// QK^T uses SWAPPED operands: mfma(K_frag, Q_frag) -> C col = q-row (l15),
// reg r = k-col quad*4+r. Each lane then holds 4 CONSECUTIVE k-cols of one
// q-row: fp32 attn store is one dwordx4, P->LDS is one ds_write_b64, and the
// softmax denominator reduces with 2 shuffles (xor 16, 32) into a scalar.
// Pass 1: lsum[half]; LDS exchange between wave pairs -> rinv.
// Pass 2: recompute s, write attn = exp(s)*rinv (fp32x4), LDS round-trip
// P -> A-layout, PV MFMA into ctx partials; wave pairs combine ctx via LDS.
// ---------------------------------------------------------------------------
__global__ __launch_bounds__(256, 8) void attn_fused(
    const unsigned short* __restrict__ q_ws, const unsigned short* __restrict__ k_ws,
    const unsigned short* __restrict__ vT_ws,
    float* __restrict__ attn_out, unsigned short* __restrict__ ctx_ws)
{
  __shared__ __align__(16) unsigned short p_lds[4][16 * 72];  // P round-trip; reused as 8KB f32 ctx-combine
  __shared__ float ls[4][16];                                  // per-wave half row-sums
  const int tid = threadIdx.x, lane = tid & 63, w = tid >> 6;
  const int l15 = lane & 15, quad = lane >> 4;
  const int rowg = w >> 1, khalf = w & 1;
  const int bh = blockIdx.x >> 6, qt = blockIdx.x & 63;
  const int qr0 = qt * 32 + rowg * 16;
  const int kc0 = khalf * 1024;

  // Q fragment (B-operand now): B[n=l15][k=quad*8+j] = contiguous 8 bf16 of q row
  const unsigned short* qp = q_ws + ((size_t)bh * S_LEN + qr0 + l15) * HDIM + quad * 8;
  bf16x8 aq0 = *(const bf16x8*)qp;
  bf16x8 aq1 = *(const bf16x8*)(qp + 32);

  const unsigned short* kbh = k_ws + (size_t)bh * S_LEN * HDIM;
  const unsigned short* vbh = vT_ws + (size_t)bh * HDIM * S_LEN;

  // ---- pass 1: lsum over this wave's key half ----
  float lsum = 0.f;
  for (int kc = kc0; kc < kc0 + 1024; kc += 64) {
#pragma unroll
    for (int t = 0; t < 4; t++) {
      const unsigned short* kb = kbh + (size_t)(kc + t * 16 + l15) * HDIM + quad * 8;
      bf16x8 b0 = *(const bf16x8*)kb;
      bf16x8 b1 = *(const bf16x8*)(kb + 32);
      f32x4 s = {0.f, 0.f, 0.f, 0.f};
      s = __builtin_amdgcn_mfma_f32_16x16x32_bf16(b0, aq0, s, 0, 0, 0);
      s = __builtin_amdgcn_mfma_f32_16x16x32_bf16(b1, aq1, s, 0, 0, 0);
      lsum += (__expf(s[0]) + __expf(s[1])) + (__expf(s[2]) + __expf(s[3]));
    }
  }
  // reduce across quads: all lanes end with their q-row (l15) half-sum
  float v = lsum;
  v += __shfl_xor(v, 16, 64);
  v += __shfl_xor(v, 32, 64);
  if (lane < 16) ls[w][lane] = v;          // quad 0 publishes
  __syncthreads();
  const float rinv = 1.0f / (v + ls[w ^ 1][l15]);  // + partner wave's half

  // ---- pass 2: attn write + PV ----
  f32x4 cacc[4] = {};
  float* abp = attn_out + ((size_t)bh * S_LEN + qr0 + l15) * S_LEN + quad * 4;
  unsigned short* plw = &p_lds[w][0];
  for (int kc = kc0; kc < kc0 + 1024; kc += 64) {
#pragma unroll
    for (int t = 0; t < 4; t++) {
      const unsigned short* kb = kbh + (size_t)(kc + t * 16 + l15) * HDIM + quad * 8;
      bf16x8 b0 = *(const bf16x8*)kb;
      bf16x8 b1 = *(const bf16x8*)(kb + 32);
      f32x4 s = {0.f, 0.f, 0.f, 0.f};
      s = __builtin_amdgcn_mfma_f32_16x16x32_bf16(b0, aq0, s, 0, 0, 0);
      s = __builtin_amdgcn_mfma_f32_16x16x32_bf16(b1, aq1, s, 0, 0, 0);
#pragma unroll
      for (int r = 0; r < 4; r++) s[r] = __expf(s[r]) * rinv;
      *(f32x4*)(abp + kc + t * 16) = s;                       // one dwordx4 / lane
      ushort4 pk;
      pk.x = f2bf(s[0]); pk.y = f2bf(s[1]); pk.z = f2bf(s[2]); pk.w = f2bf(s[3]);
      *(ushort4*)(plw + l15 * 72 + t * 16 + quad * 4) = pk;   // [q-row][k-col] -> LDS
    }
    // read back in A-layout (same wave; compiler inserts lgkmcnt waits)
    bf16x8 ap0 = *(const bf16x8*)(plw + l15 * 72 + quad * 8);
    bf16x8 ap1 = *(const bf16x8*)(plw + l15 * 72 + 32 + quad * 8);
#pragma unroll
    for (int dt = 0; dt < 4; dt++) {
      const unsigned short* vb = vbh + (size_t)(dt * 16 + l15) * S_LEN + kc + quad * 8;
      bf16x8 v0 = *(const bf16x8*)vb;
      bf16x8 v1 = *(const bf16x8*)(vb + 32);
      cacc[dt] = __builtin_amdgcn_mfma_f32_16x16x32_bf16(ap0, v0, cacc[dt], 0, 0, 0);
      cacc[dt] = __builtin_amdgcn_mfma_f32_16x16x32_bf16(ap1, v1, cacc[dt], 0, 0, 0);
    }
  }

  // ---- combine ctx partials across wave pairs (odd half -> LDS -> even adds) ----
  __syncthreads();                           // p_lds P-use done; reuse as f32 scratch
  float* cb = (float*)&p_lds[0][0];          // 2 rowg * 64 lanes * 16 f = 8KB <= 9216B
  if (khalf) {
#pragma unroll
    for (int dt = 0; dt < 4; dt++)
      *(f32x4*)(cb + (rowg * 64 + lane) * 16 + dt * 4) = cacc[dt];
  }
  __syncthreads();
  if (!khalf) {
#pragma unroll
    for (int dt = 0; dt < 4; dt++)
      cacc[dt] += *(const f32x4*)(cb + (rowg * 64 + lane) * 16 + dt * 4);
    // ctx -> [B,S,H,HD] bf16 (token-major rows of 1024 for the output GEMM)
    const int b = bh >> 4, h = bh & 15;
#pragma unroll
    for (int dt = 0; dt < 4; dt++)
#pragma unroll
      for (int r = 0; r < 4; r++) {
        const int s_ = qr0 + quad * 4 + r;
        const int d = dt * 16 + l15;
        ctx_ws[((size_t)(b * S_LEN + s_) * NH + h) * HDIM + d] = f2bf(cacc[dt][r]);
      }
  }
}

// ---------------------------------------------------------------------------
// out = ctx @ Wo^T + bo  (fp32 output)
// ---------------------------------------------------------------------------
__global__ __launch_bounds__(256) void gemm_out(
    const unsigned short* __restrict__ ctx, const unsigned short* __restrict__ wo,
    const float* __restrict__ bo, float* __restrict__ out)
{
  __shared__ unsigned short Al[128 * 32];
  __shared__ unsigned short Bl[128 * 32];
  const int m0 = blockIdx.y * 128, n0 = blockIdx.x * 128;
  const int tid = threadIdx.x, lane = tid & 63;
  const int wm = ((tid >> 6) >> 1) * 64, wn = ((tid >> 6) & 1) * 64;
  const int l15 = lane & 15, quad = lane >> 4;
  f32x4 acc[4][4] = {};
  gemm_core_128(ctx, wo, Al, Bl, m0, n0, tid, acc);
#pragma unroll
  for (int j = 0; j < 4; j++) {
    const int n = n0 + wn + j * 16 + l15;
    const float bb = bo[n];
#pragma unroll
    for (int i = 0; i < 4; i++)
#pragma unroll
      for (int r = 0; r < 4; r++) {
        const int m = m0 + wm + i * 16 + quad * 4 + r;
        out[(size_t)m * DMODEL + n] = acc[i][j][r] + bb;
      }
  }
}

// ---------------------------------------------------------------------------
extern "C" void kernel_launch(void* const* d_in, const int* in_sizes, int n_in,
                              void* d_out, int out_size, void* d_ws, size_t ws_size,
                              hipStream_t stream) {
  const float* x  = (const float*)d_in[0];
  const float* Wq = (const float*)d_in[1];
  const float* bq = (const float*)d_in[2];
  const float* Wk = (const float*)d_in[3];
  const float* bk = (const float*)d_in[4];
  const float* Wv = (const float*)d_in[5];
  const float* bv = (const float*)d_in[6];
  const float* Wo = (const float*)d_in[7];
  const float* bo = (const float*)d_in[8];

  const size_t MB = 1u << 20;
  char* ws = (char*)d_ws;
  unsigned short* xb     = (unsigned short*)(ws);             // 8 MB  [4096,1024] bf16
  unsigned short* wqb    = (unsigned short*)(ws + 8 * MB);    // 2 MB
  unsigned short* wkb    = (unsigned short*)(ws + 10 * MB);   // 2 MB
  unsigned short* wvb    = (unsigned short*)(ws + 12 * MB);   // 2 MB
  unsigned short* wob    = (unsigned short*)(ws + 14 * MB);   // 2 MB
  unsigned short* q_ws   = (unsigned short*)(ws + 16 * MB);   // 8 MB  [B,H,S,HD]
  unsigned short* k_ws   = (unsigned short*)(ws + 24 * MB);   // 8 MB  [B,H,S,HD]
  unsigned short* vT_ws  = (unsigned short*)(ws + 32 * MB);   // 8 MB  [B,H,HD,S]
  unsigned short* ctx_ws = (unsigned short*)(ws + 40 * MB);   // 8 MB  [B,S,H,HD]

  float* out_ptr  = (float*)d_out;                  // [2,2048,1024]
  float* attn_ptr = (float*)d_out + 4194304;        // [2,16,2048,2048]

  cvt_kernel<<<4096, 256, 0, stream>>>(x,  xb,  4194304);
  cvt_kernel<<<1024, 256, 0, stream>>>(Wq, wqb, 1048576);
  cvt_kernel<<<1024, 256, 0, stream>>>(Wk, wkb, 1048576);
  cvt_kernel<<<1024, 256, 0, stream>>>(Wv, wvb, 1048576);
  cvt_kernel<<<1024, 256, 0, stream>>>(Wo, wob, 1048576);

  gemm_qkv<<<dim3(8, 32, 3), 256, 0, stream>>>(xb, wqb, wkb, wvb, bq, bk, bv,
                                               q_ws, k_ws, vT_ws);
  attn_fused<<<2048, 256, 0, stream>>>(q_ws, k_ws, vT_ws, attn_ptr, ctx_ws);
  gemm_out<<<dim3(8, 32, 1), 256, 0, stream>>>(ctx_ws, wob, bo, out_ptr);
}

// Round 3
// 826.217 us; speedup vs baseline: 1.2288x; 1.2227x over previous
//
#include <hip/hip_runtime.h>

// Problem constants: B=2, S=2048, D=1024, H=16, HD=64
#define S_LEN 2048
#define NH 16
#define HDIM 64
#define DMODEL 1024
#define NTOK 4096  // B*S
#define RSW 2060   // S_lds row stride in words (2048 + 12 pad; 2060%32==12 spreads banks)

typedef __attribute__((ext_vector_type(8))) short bf16x8;   // 8 bf16 = 4 VGPRs (MFMA A/B frag)
typedef __attribute__((ext_vector_type(4))) float f32x4;    // MFMA C/D frag

__device__ __forceinline__ unsigned short f2bf(float f) {
  union { float f; unsigned int u; } a; a.f = f;
  unsigned int u = a.u;
  u += 0x7FFFu + ((u >> 16) & 1u);   // RNE
  return (unsigned short)(u >> 16);
}

__device__ __forceinline__ void gld_lds16(const unsigned short* g, unsigned short* l) {
  auto gp = (const __attribute__((address_space(1))) unsigned short*)(g);
  auto lp = (__attribute__((address_space(3))) unsigned short*)(l);
  __builtin_amdgcn_global_load_lds(gp, lp, 16, 0, 0);   // 16B per lane, async to LDS
}

// ---------------------------------------------------------------------------
// fp32 -> bf16 convert (n multiple of 4)
// ---------------------------------------------------------------------------
__global__ __launch_bounds__(256) void cvt_kernel(const float* __restrict__ s,
                                                  unsigned short* __restrict__ d, int n) {
  int i = (blockIdx.x * 256 + threadIdx.x) * 4;
  if (i >= n) return;
  float4 v = *(const float4*)(s + i);
  ushort4 o;
  o.x = f2bf(v.x); o.y = f2bf(v.y); o.z = f2bf(v.z); o.w = f2bf(v.w);
  *(ushort4*)(d + i) = o;
}

// ---------------------------------------------------------------------------
// GEMM core: C(128x128) = A[M,K=1024] * B[N,K=1024]^T, bf16 inputs, K-loop BK=32.
// m97 structure: global_load_lds width16 staging, 8 ds_read_b128 + 16 MFMA / iter.
// ---------------------------------------------------------------------------
__device__ __forceinline__ void gemm_core_128(
    const unsigned short* __restrict__ A, const unsigned short* __restrict__ B,
    unsigned short* Al, unsigned short* Bl, int m0, int n0, int tid, f32x4 acc[4][4])
{
  const int lane = tid & 63;
  const int wm = ((tid >> 6) >> 1) * 64;
  const int wn = ((tid >> 6) & 1) * 64;
  const int l15 = lane & 15, quad = lane >> 4;
  const int row0 = tid >> 2, c8 = (tid & 3) * 8;
  for (int kk = 0; kk < DMODEL; kk += 32) {
    gld_lds16(A + (size_t)(m0 + row0) * DMODEL + kk + c8,      Al + tid * 8);
    gld_lds16(A + (size_t)(m0 + 64 + row0) * DMODEL + kk + c8, Al + (256 + tid) * 8);
    gld_lds16(B + (size_t)(n0 + row0) * DMODEL + kk + c8,      Bl + tid * 8);
    gld_lds16(B + (size_t)(n0 + 64 + row0) * DMODEL + kk + c8, Bl + (256 + tid) * 8);
    __syncthreads();   // compiler emits vmcnt(0) drain before s_barrier
    bf16x8 af[4], bfr[4];
#pragma unroll
    for (int i = 0; i < 4; i++) {
      af[i]  = *(const bf16x8*)(Al + (wm + i * 16 + l15) * 32 + quad * 8);
      bfr[i] = *(const bf16x8*)(Bl + (wn + i * 16 + l15) * 32 + quad * 8);
    }
#pragma unroll
    for (int i = 0; i < 4; i++)
#pragma unroll
      for (int j = 0; j < 4; j++)
        acc[i][j] = __builtin_amdgcn_mfma_f32_16x16x32_bf16(af[i], bfr[j], acc[i][j], 0, 0, 0);
    __syncthreads();
  }
}

// ---------------------------------------------------------------------------
// QKV projection: z=0 -> q (pre-scaled by 1/8), z=1 -> k, z=2 -> v transposed.
// q,k layout [B,H,S,HD]; vT layout [B,H,HD,S].
// C/D frag mapping (m89-verified): col = lane&15, row = quad*4 + reg.
// ---------------------------------------------------------------------------
__global__ __launch_bounds__(256) void gemm_qkv(
    const unsigned short* __restrict__ xb,
    const unsigned short* __restrict__ wq, const unsigned short* __restrict__ wk,
    const unsigned short* __restrict__ wv,
    const float* __restrict__ bq, const float* __restrict__ bk, const float* __restrict__ bv,
    unsigned short* __restrict__ q_ws, unsigned short* __restrict__ k_ws,
    unsigned short* __restrict__ vT_ws)
{
  __shared__ unsigned short Al[128 * 32];
  __shared__ unsigned short Bl[128 * 32];
  const int which = blockIdx.z;
  const unsigned short* W = which == 0 ? wq : (which == 1 ? wk : wv);
  const float* bias = which == 0 ? bq : (which == 1 ? bk : bv);
  const int m0 = blockIdx.y * 128, n0 = blockIdx.x * 128;
  const int tid = threadIdx.x, lane = tid & 63;
  const int wm = ((tid >> 6) >> 1) * 64, wn = ((tid >> 6) & 1) * 64;
  const int l15 = lane & 15, quad = lane >> 4;
  f32x4 acc[4][4] = {};
  gemm_core_128(xb, W, Al, Bl, m0, n0, tid, acc);
  const float scale = (which == 0) ? 0.125f : 1.0f;   // fold 1/sqrt(HD) into q
  unsigned short* qk_dst = (which == 0) ? q_ws : k_ws;
#pragma unroll
  for (int j = 0; j < 4; j++) {
    const int n = n0 + wn + j * 16 + l15;
    const float bb = bias[n];
    const int h = n >> 6, d = n & 63;
#pragma unroll
    for (int i = 0; i < 4; i++)
#pragma unroll
      for (int r = 0; r < 4; r++) {
        const int m = m0 + wm + i * 16 + quad * 4 + r;
        const int b = m >> 11, s = m & 2047;
        const unsigned short o = f2bf((acc[i][j][r] + bb) * scale);
        if (which == 2)
          vT_ws[((size_t)(b * NH + h) * HDIM + d) * S_LEN + s] = o;
        else
          qk_dst[((size_t)(b * NH + h) * S_LEN + s) * HDIM + d] = o;
      }
  }
}

// ---------------------------------------------------------------------------
// Fused attention, sequential-write version (hardened: plain __syncthreads only).
// Grid: 4096 blocks = 32 bh * 128 q-tiles of 16 rows; 512 threads = 8 waves.
// Single pass over K: wave w owns kc range [w*256, w*256+256).
//  phase 1: exp(q.K^T) for 16 rows x own-256 cols -> fp32 LDS tile
//           (16 x 2048, ~129 KB), accumulate per-row partial sums.
//           Swapped MFMA: mfma(K,Q) -> q-row = lane&15, k-col = quad*4+reg.
//  phase 2: PV on raw exp values from LDS (rinv folded into ctx at the end).
//  phase 3: stream-out: wave w writes rows {2w, 2w+1} of attn = exp*rinv as
//           fully SEQUENTIAL 1KB-per-instruction fp32 NONTEMPORAL stores
//           (8KB run per row). Theory: the 536MB attn write drained at
//           1.28 TB/s because of 64B-granule writes scattered over ~100K
//           8KB-strided rows (DRAM page thrash); sequential runs fix it,
//           and nt keeps the write-once stream from evicting K/V in L2.
//  phase 4: combine 8 kc-partial ctx accumulators via LDS (S region reused).
// ---------------------------------------------------------------------------
__global__ __launch_bounds__(512, 1) void attn_fused(
    const unsigned short* __restrict__ q_ws, const unsigned short* __restrict__ k_ws,
    const unsigned short* __restrict__ vT_ws,
    float* __restrict__ attn_out, unsigned short* __restrict__ ctx_ws)
{
  __shared__ float S_lds[16 * RSW];   // 131,840 B
  __shared__ float ls[8][16];         // per-wave partial row sums
  const int tid = threadIdx.x, lane = tid & 63, w = tid >> 6;
  const int l15 = lane & 15, quad = lane >> 4;
  const int bh = blockIdx.x >> 7, qt = blockIdx.x & 127;
  const int qr0 = qt * 16;
  const int kc0 = w * 256;

  // Q fragment (B-operand of swapped QK^T): B[n=l15][k=quad*8+j]
  const unsigned short* qp = q_ws + ((size_t)bh * S_LEN + qr0 + l15) * HDIM + quad * 8;
  const bf16x8 aq0 = *(const bf16x8*)qp;
  const bf16x8 aq1 = *(const bf16x8*)(qp + 32);
  const unsigned short* kbh = k_ws + (size_t)bh * S_LEN * HDIM;
  const unsigned short* vbh = vT_ws + (size_t)bh * HDIM * S_LEN;

  // ---- phase 1: exp(scores) -> LDS, partial row sums ----
  float lsum = 0.f;
  for (int kc = kc0; kc < kc0 + 256; kc += 64) {
#pragma unroll
    for (int t = 0; t < 4; t++) {
      const unsigned short* kb = kbh + (size_t)(kc + t * 16 + l15) * HDIM + quad * 8;
      bf16x8 b0 = *(const bf16x8*)kb;
      bf16x8 b1 = *(const bf16x8*)(kb + 32);
      f32x4 s = {0.f, 0.f, 0.f, 0.f};
      s = __builtin_amdgcn_mfma_f32_16x16x32_bf16(b0, aq0, s, 0, 0, 0);
      s = __builtin_amdgcn_mfma_f32_16x16x32_bf16(b1, aq1, s, 0, 0, 0);
      f32x4 e;
#pragma unroll
      for (int r = 0; r < 4; r++) e[r] = __expf(s[r]);
      lsum += (e[0] + e[1]) + (e[2] + e[3]);
      // row = l15, cols = kc + t*16 + quad*4 + {0..3}
      *(f32x4*)&S_lds[l15 * RSW + kc + t * 16 + quad * 4] = e;
    }
  }
  {
    float v = lsum;
    v += __shfl_xor(v, 16, 64);   // sum over quads -> lane holds row(l15) partial
    v += __shfl_xor(v, 32, 64);
    if (lane < 16) ls[w][lane] = v;
  }
  __syncthreads();   // all S columns + partial sums visible

  // rinv for this wave's two output rows (rows 2w, 2w+1)
  const int row0 = w * 2;
  float t0 = 0.f, t1 = 0.f;
#pragma unroll
  for (int wv = 0; wv < 8; wv++) { t0 += ls[wv][row0]; t1 += ls[wv][row0 + 1]; }
  const float rinv0 = 1.0f / t0, rinv1 = 1.0f / t1;

  // ---- phase 2: PV partial over own kc range (raw exp; rinv folded later) ----
  f32x4 cacc[4] = {};
  for (int kk = 0; kk < 256; kk += 32) {
    const int base = l15 * RSW + kc0 + kk + quad * 8;   // A[m=l15][k=quad*8+j]
    f32x4 pa = *(const f32x4*)&S_lds[base];
    f32x4 pb = *(const f32x4*)&S_lds[base + 4];
    bf16x8 ap;
#pragma unroll
    for (int j = 0; j < 4; j++) {
      ap[j]     = (short)f2bf(pa[j]);
      ap[4 + j] = (short)f2bf(pb[j]);
    }
#pragma unroll
    for (int dt = 0; dt < 4; dt++) {
      const unsigned short* vb = vbh + (size_t)(dt * 16 + l15) * S_LEN + kc0 + kk + quad * 8;
      bf16x8 v0 = *(const bf16x8*)vb;
      cacc[dt] = __builtin_amdgcn_mfma_f32_16x16x32_bf16(ap, v0, cacc[dt], 0, 0, 0);
    }
  }

  // ---- phase 3: sequential nontemporal stream-out of rows 2w, 2w+1 ----
  {
    float* g0 = attn_out + ((size_t)bh * S_LEN + qr0 + row0) * S_LEN;
    float* g1 = g0 + S_LEN;
#pragma unroll
    for (int c = 0; c < 8; c++) {
      f32x4 v0 = *(const f32x4*)&S_lds[row0 * RSW + c * 256 + lane * 4];
      f32x4 v1 = *(const f32x4*)&S_lds[(row0 + 1) * RSW + c * 256 + lane * 4];
#pragma unroll
      for (int j = 0; j < 4; j++) { v0[j] *= rinv0; v1[j] *= rinv1; }
      __builtin_nontemporal_store(v0, (f32x4*)(g0 + c * 256 + lane * 4));  // 1KB/instr contiguous
      __builtin_nontemporal_store(v1, (f32x4*)(g1 + c * 256 + lane * 4));
    }
  }

  __syncthreads();   // all S_lds reads done; safe to reuse as combine scratch

  // ---- phase 4: combine 8 kc-partials (reuse S region: [8][16][64] f32) ----
  float* comb = &S_lds[0];
#pragma unroll
  for (int dt = 0; dt < 4; dt++)
#pragma unroll
    for (int r = 0; r < 4; r++)
      comb[w * 1024 + (quad * 4 + r) * 64 + dt * 16 + l15] = cacc[dt][r];
  __syncthreads();

  const int b = bh >> 4, h = bh & 15;
  float c0 = 0.f, c1 = 0.f;
#pragma unroll
  for (int wv = 0; wv < 8; wv++) {
    c0 += comb[wv * 1024 + row0 * 64 + lane];
    c1 += comb[wv * 1024 + (row0 + 1) * 64 + lane];
  }
  ctx_ws[((size_t)(b * S_LEN + qr0 + row0) * NH + h) * HDIM + lane]     = f2bf(c0 * rinv0);
  ctx_ws[((size_t)(b * S_LEN + qr0 + row0 + 1) * NH + h) * HDIM + lane] = f2bf(c1 * rinv1);
}

// ---------------------------------------------------------------------------
// out = ctx @ Wo^T + bo  (fp32 output)
// ---------------------------------------------------------------------------
__global__ __launch_bounds__(256) void gemm_out(
    const unsigned short* __restrict__ ctx, const unsigned short* __restrict__ wo,
    const float* __restrict__ bo, float* __restrict__ out)
{
  __shared__ unsigned short Al[128 * 32];
  __shared__ unsigned short Bl[128 * 32];
  const int m0 = blockIdx.y * 128, n0 = blockIdx.x * 128;
  const int tid = threadIdx.x, lane = tid & 63;
  const int wm = ((tid >> 6) >> 1) * 64, wn = ((tid >> 6) & 1) * 64;
  const int l15 = lane & 15, quad = lane >> 4;
  f32x4 acc[4][4] = {};
  gemm_core_128(ctx, wo, Al, Bl, m0, n0, tid, acc);
#pragma unroll
  for (int j = 0; j < 4; j++) {
    const int n = n0 + wn + j * 16 + l15;
    const float bb = bo[n];
#pragma unroll
    for (int i = 0; i < 4; i++)
#pragma unroll
      for (int r = 0; r < 4; r++) {
        const int m = m0 + wm + i * 16 + quad * 4 + r;
        out[(size_t)m * DMODEL + n] = acc[i][j][r] + bb;
      }
  }
}

// ---------------------------------------------------------------------------
extern "C" void kernel_launch(void* const* d_in, const int* in_sizes, int n_in,
                              void* d_out, int out_size, void* d_ws, size_t ws_size,
                              hipStream_t stream) {
  const float* x  = (const float*)d_in[0];
  const float* Wq = (const float*)d_in[1];
  const float* bq = (const float*)d_in[2];
  const float* Wk = (const float*)d_in[3];
  const float* bk = (const float*)d_in[4];
  const float* Wv = (const float*)d_in[5];
  const float* bv = (const float*)d_in[6];
  const float* Wo = (const float*)d_in[7];
  const float* bo = (const float*)d_in[8];

  const size_t MB = 1u << 20;
  char* ws = (char*)d_ws;
  unsigned short* xb     = (unsigned short*)(ws);             // 8 MB  [4096,1024] bf16
  unsigned short* wqb    = (unsigned short*)(ws + 8 * MB);    // 2 MB
  unsigned short* wkb    = (unsigned short*)(ws + 10 * MB);   // 2 MB
  unsigned short* wvb    = (unsigned short*)(ws + 12 * MB);   // 2 MB
  unsigned short* wob    = (unsigned short*)(ws + 14 * MB);   // 2 MB
  unsigned short* q_ws   = (unsigned short*)(ws + 16 * MB);   // 8 MB  [B,H,S,HD]
  unsigned short* k_ws   = (unsigned short*)(ws + 24 * MB);   // 8 MB  [B,H,S,HD]
  unsigned short* vT_ws  = (unsigned short*)(ws + 32 * MB);   // 8 MB  [B,H,HD,S]
  unsigned short* ctx_ws = (unsigned short*)(ws + 40 * MB);   // 8 MB  [B,S,H,HD]

  float* out_ptr  = (float*)d_out;                  // [2,2048,1024]
  float* attn_ptr = (float*)d_out + 4194304;        // [2,16,2048,2048]

  cvt_kernel<<<4096, 256, 0, stream>>>(x,  xb,  4194304);
  cvt_kernel<<<1024, 256, 0, stream>>>(Wq, wqb, 1048576);
  cvt_kernel<<<1024, 256, 0, stream>>>(Wk, wkb, 1048576);
  cvt_kernel<<<1024, 256, 0, stream>>>(Wv, wvb, 1048576);
  cvt_kernel<<<1024, 256, 0, stream>>>(Wo, wob, 1048576);

  gemm_qkv<<<dim3(8, 32, 3), 256, 0, stream>>>(xb, wqb, wkb, wvb, bq, bk, bv,
                                               q_ws, k_ws, vT_ws);
  attn_fused<<<4096, 512, 0, stream>>>(q_ws, k_ws, vT_ws, attn_ptr, ctx_ws);
  gemm_out<<<dim3(8, 32, 1), 256, 0, stream>>>(ctx_ws, wob, bo, out_ptr);
}